// Round 11
// baseline (221.847 us; speedup 1.0000x reference)
//
#include <hip/hip_runtime.h>

typedef unsigned short u16;
typedef unsigned int u32;

#define NN 50000
#define NR 8
#define NE 100000

typedef __bf16 bf16x8 __attribute__((ext_vector_type(8)));
typedef float f32x4 __attribute__((ext_vector_type(4)));

__device__ __forceinline__ float bf2f(u16 b){ return __uint_as_float(((u32)b) << 16); }
__device__ __forceinline__ u16 f2bf(float x){
    u32 u = __float_as_uint(x);
    u += 0x7fffu + ((u >> 16) & 1u);
    return (u16)(u >> 16);
}

// K0: detect device float dtype (block 0) + zero cursor array. flag: 0=bf16, 1=f32
__global__ void k_detect_zero(const u16* __restrict__ feat, int* __restrict__ flag,
                              int* __restrict__ cursP){
    int t = blockIdx.x * 256 + threadIdx.x;   // 0..799999 exact = 50000*16 cursor ints
    cursP[t] = 0;
    if (blockIdx.x == 0 && threadIdx.x < 64){
        u16 v = feat[2 * threadIdx.x * 1001];
        int e = (v >> 7) & 0xFF;
        unsigned long long m = __ballot(e >= 96 && e <= 158);
        if (threadIdx.x == 0) *flag = (__popcll(m) >= 40) ? 0 : 1;
    }
}

// K1: fused prep. 800000 threads, three independent jobs:
//  (a) featB normalize (16B chunk)
//  (b) flat per-dst edge bucket: slots48[dst][pos] = (rel<<16)|src, one atomic
//      on a 64B-padded cursor line (cursP stride 16 u32)
//  (c) BT weights (first 147456 threads)
__global__ void k_prep(const void* __restrict__ feat_, const int* __restrict__ esrc,
                       const int* __restrict__ edst, const void* __restrict__ bases_,
                       const void* __restrict__ coeff_, const void* __restrict__ selfw_,
                       u16* __restrict__ featB, u16* __restrict__ BT,
                       int* __restrict__ cursP, u32* __restrict__ slots48,
                       const int* __restrict__ flag){
    int t = blockIdx.x * 256 + threadIdx.x;   // 0..799999 exact
    int isf = *flag;

    // (a) normalize feat chunk t
    if (isf){
        const float4* ff = (const float4*)feat_;
        float4 a = ff[t*2], b = ff[t*2 + 1];
        uint4 o;
        o.x = (u32)f2bf(a.x) | ((u32)f2bf(a.y) << 16);
        o.y = (u32)f2bf(a.z) | ((u32)f2bf(a.w) << 16);
        o.z = (u32)f2bf(b.x) | ((u32)f2bf(b.y) << 16);
        o.w = (u32)f2bf(b.z) | ((u32)f2bf(b.w) << 16);
        ((uint4*)featB)[t] = o;
    } else {
        ((uint4*)featB)[t] = ((const uint4*)feat_)[t];
    }

    // (b) bucket edge t
    {
        int r = t / NE;
        int dst = edst[t];
        int src = esrc[t];
        int pos = atomicAdd(&cursP[dst*16], 1);
        if (pos < 48) slots48[(size_t)dst*48 + pos] = ((u32)r << 16) | (u32)src;
    }

    // (c) weights elem t
    if (t < 147456){
        int row = t >> 7, i = t & 127;
        float v;
        if (isf){
            const float* bases = (const float*)bases_;
            const float* coeff = (const float*)coeff_;
            const float* selfw = (const float*)selfw_;
            if (row < 1024){
                int r = row >> 7, o = row & 127;
                v = 0.f;
                #pragma unroll
                for (int b = 0; b < 8; b++)
                    v += coeff[r*8 + b] * bases[(b*128 + i)*128 + o];
            } else {
                v = selfw[i*128 + (row - 1024)];
            }
        } else {
            const u16* bases = (const u16*)bases_;
            const u16* coeff = (const u16*)coeff_;
            const u16* selfw = (const u16*)selfw_;
            if (row < 1024){
                int r = row >> 7, o = row & 127;
                v = 0.f;
                #pragma unroll
                for (int b = 0; b < 8; b++)
                    v += bf2f(coeff[r*8 + b]) * bf2f(bases[(b*128 + i)*128 + o]);
            } else {
                v = bf2f(selfw[i*128 + (row - 1024)]);
            }
        }
        BT[row*128 + i] = f2bf(v);
    }
}

// K2: fused aggregate + transform + LayerNorm.
// Block = 1024 threads (16 waves) per 16 dst nodes; grid 3125 (exact).
// Gather: ONE flat loop over the node's <=48 edges, batches of 4 independent
// clamped-index row loads (full MLP), accumulate into 8 static float2 accs
// via readfirstlane-scalarized relation branch. Per-rel counts from ballots.
// Then: 9-slice MFMA (waves 0..7, 16-col stripes) + fused LayerNorm.
__global__ __launch_bounds__(1024, 8) void k_fused(
        const u16* __restrict__ featB, const u16* __restrict__ BT,
        const u32* __restrict__ slots48, const int* __restrict__ cursP,
        const void* __restrict__ gamma_, const void* __restrict__ beta_,
        void* __restrict__ out_, const int* __restrict__ flag){
    __shared__ __align__(16) char sm[39168 + 3072];
    u16 (*As)[16][136] = (u16 (*)[16][136])sm;            // [9][16][136] bf16
    u32 (*ssl)[48]     = (u32 (*)[48])(sm + 39168);       // [16][48]
    float (*Cs)[132]   = (float (*)[132])sm;              // epilogue alias 8448 B

    int tid  = threadIdx.x;
    int lane = tid & 63, wv = tid >> 6;    // wv 0..15
    int node = blockIdx.x * 16 + wv;       // < 50000 exact
    const u32* fB = (const u32*)featB;

    // stage: edge count, slot table, self row
    int cT = cursP[node*16]; cT = cT < 48 ? cT : 48;
    u32 myw = 0xFFFFFFFFu;
    if (lane < 48){
        myw = slots48[(size_t)node*48 + lane];
        ssl[wv][lane] = myw;
    }
    if (lane >= cT) myw = 0xFFFFFFFFu;
    u32 selfv = fB[(size_t)node*64 + lane];
    __builtin_amdgcn_s_waitcnt(0);

    // per-relation counts via ballots (lane p holds slot p)
    int relv = (int)(myw >> 16);
    float inv0, inv1, inv2, inv3, inv4, inv5, inv6, inv7;
    #define CNT(r) { int c_ = __popcll(__ballot(relv == r)); \
                     inv##r = 1.0f / (float)(c_ < 1 ? 1 : c_); }
    CNT(0) CNT(1) CNT(2) CNT(3) CNT(4) CNT(5) CNT(6) CNT(7)
    #undef CNT

    // flat edge loop, batches of 4 clamped-index loads
    float2 a0 = {0,0}, a1 = {0,0}, a2 = {0,0}, a3 = {0,0};
    float2 a4 = {0,0}, a5 = {0,0}, a6 = {0,0}, a7 = {0,0};
    #pragma unroll 1
    for (int p = 0; p < cT; p += 4){
        int cm = cT - 1;
        int p1 = (p+1 < cm) ? p+1 : cm;
        int p2 = (p+2 < cm) ? p+2 : cm;
        int p3 = (p+3 < cm) ? p+3 : cm;
        u32 w0 = ssl[wv][p],  w1 = ssl[wv][p1];
        u32 w2 = ssl[wv][p2], w3 = ssl[wv][p3];
        u32 v0 = fB[(size_t)(w0 & 0xffffu)*64 + lane];
        u32 v1 = fB[(size_t)(w1 & 0xffffu)*64 + lane];
        u32 v2 = fB[(size_t)(w2 & 0xffffu)*64 + lane];
        u32 v3 = fB[(size_t)(w3 & 0xffffu)*64 + lane];
        #define ACC(i) if (p + i < cT){ \
            int rr = (int)(__builtin_amdgcn_readfirstlane(w##i) >> 16); \
            float fx = __uint_as_float(v##i << 16); \
            float fy = __uint_as_float(v##i & 0xffff0000u); \
            if      (rr == 0){ a0.x += fx; a0.y += fy; } \
            else if (rr == 1){ a1.x += fx; a1.y += fy; } \
            else if (rr == 2){ a2.x += fx; a2.y += fy; } \
            else if (rr == 3){ a3.x += fx; a3.y += fy; } \
            else if (rr == 4){ a4.x += fx; a4.y += fy; } \
            else if (rr == 5){ a5.x += fx; a5.y += fy; } \
            else if (rr == 6){ a6.x += fx; a6.y += fy; } \
            else             { a7.x += fx; a7.y += fy; } }
        ACC(0) ACC(1) ACC(2) ACC(3)
        #undef ACC
    }

    // write As rows: 8 relation means + self
    #define WR(r) *(u32*)&As[r][wv][2*lane] = \
        (u32)f2bf(a##r.x * inv##r) | ((u32)f2bf(a##r.y * inv##r) << 16);
    WR(0) WR(1) WR(2) WR(3) WR(4) WR(5) WR(6) WR(7)
    #undef WR
    *(u32*)&As[8][wv][2*lane] = selfv;

    __syncthreads();                       // As complete

    // MFMA: wave wv<8 owns out-cols [wv*16, wv*16+16), all 9 slices accumulate
    f32x4 acc = (f32x4)0.f;
    int la = lane & 15, lb = lane >> 4;
    if (wv < 8){
        #pragma unroll
        for (int r = 0; r < 9; r++){
            int brow = (r*128 + wv*16 + la)*128;
            #pragma unroll
            for (int ks = 0; ks < 4; ks++){
                bf16x8 bfr = *(const bf16x8*)&BT[brow + ks*32 + lb*8];
                bf16x8 af  = *(const bf16x8*)&As[r][la][ks*32 + lb*8];
                acc = __builtin_amdgcn_mfma_f32_16x16x32_bf16(bfr, af, acc, 0, 0, 0);
            }
        }
    }
    __syncthreads();                       // all As reads done (Cs aliases As)

    if (wv < 8)
        *(f32x4*)&Cs[la][wv*16 + lb*4] = acc;   // row=node-in-tile, col=out-col
    __syncthreads();

    // LayerNorm: wave wv handles its node's row; lane = col-pair
    int isf = *flag;
    float2 xv = *(const float2*)&Cs[wv][2*lane];
    float s = xv.x + xv.y, q = xv.x*xv.x + xv.y*xv.y;
    #pragma unroll
    for (int off = 32; off; off >>= 1){
        s += __shfl_xor(s, off, 64);
        q += __shfl_xor(q, off, 64);
    }
    float mean = s * (1.f/128.f);
    float var  = q * (1.f/128.f) - mean*mean;
    float rstd = rsqrtf(fmaxf(var, 0.f) + 1e-5f);
    float g0, g1, b0, b1;
    if (isf){
        float2 gv = ((const float2*)gamma_)[lane];
        float2 bv = ((const float2*)beta_)[lane];
        g0 = gv.x; g1 = gv.y; b0 = bv.x; b1 = bv.y;
    } else {
        u32 gv = ((const u32*)gamma_)[lane];
        u32 bv = ((const u32*)beta_)[lane];
        g0 = __uint_as_float(gv << 16); g1 = __uint_as_float(gv & 0xffff0000u);
        b0 = __uint_as_float(bv << 16); b1 = __uint_as_float(bv & 0xffff0000u);
    }
    float y0 = (xv.x - mean)*rstd*g0 + b0;
    float y1 = (xv.y - mean)*rstd*g1 + b1;
    if (isf){
        ((float2*)out_)[(size_t)node*64 + lane] = make_float2(y0, y1);
    } else {
        ((u32*)out_)[(size_t)node*64 + lane] =
            (u32)f2bf(y0) | ((u32)f2bf(y1) << 16);
    }
}

extern "C" void kernel_launch(void* const* d_in, const int* in_sizes, int n_in,
                              void* d_out, int out_size, void* d_ws, size_t ws_size,
                              hipStream_t stream){
    const void* feat  = d_in[0];
    const int*  esrc  = (const int*)d_in[1];
    const int*  edst  = (const int*)d_in[2];
    const void* bases = d_in[3];
    const void* coeff = d_in[4];
    const void* selfw = d_in[5];
    const void* gamma = d_in[6];
    const void* beta  = d_in[7];

    char* ws = (char*)d_ws;
    int*   flag    = (int*)(ws);                    // 256
    u16*   BT      = (u16*)(ws + 256);              // 294,912
    int*   cursP   = (int*)(ws + 295168);           // 3,200,000 (50000 x 16 u32, 64B stride)
    u32*   slots48 = (u32*)(ws + 3495168);          // 9,600,000 (50000 x 48 u32)
    u16*   featB   = (u16*)(ws + 13095168);         // 12,800,000
    // total 25,895,168 B

    k_detect_zero<<<3125, 256, 0, stream>>>((const u16*)feat, flag, cursP);
    k_prep<<<3125, 256, 0, stream>>>(feat, esrc, edst, bases, coeff, selfw,
                                     featB, BT, cursP, slots48, flag);
    k_fused<<<3125, 1024, 0, stream>>>(featB, BT, slots48, cursP, gamma, beta,
                                       d_out, flag);
}

// Round 12
// 187.405 us; speedup vs baseline: 1.1838x; 1.1838x over previous
//
#include <hip/hip_runtime.h>

typedef unsigned short u16;
typedef unsigned int u32;

#define NN 50000
#define NR 8
#define NE 100000

typedef __bf16 bf16x8 __attribute__((ext_vector_type(8)));
typedef float f32x4 __attribute__((ext_vector_type(4)));

__device__ __forceinline__ float bf2f(u16 b){ return __uint_as_float(((u32)b) << 16); }
__device__ __forceinline__ u16 f2bf(float x){
    u32 u = __float_as_uint(x);
    u += 0x7fffu + ((u >> 16) & 1u);
    return (u16)(u >> 16);
}

// K0: detect device float dtype (block 0) + zero cnt. flag: 0=bf16, 1=f32
__global__ void k_detect_zero(const u16* __restrict__ feat, int* __restrict__ flag,
                              int* __restrict__ cnt){
    int t = blockIdx.x * 256 + threadIdx.x;   // grid 1563*256 = 400128
    if (t < NR*NN) cnt[t] = 0;
    if (blockIdx.x == 0 && threadIdx.x < 64){
        u16 v = feat[2 * threadIdx.x * 1001];
        int e = (v >> 7) & 0xFF;
        unsigned long long m = __ballot(e >= 96 && e <= 158);
        if (threadIdx.x == 0) *flag = (__popcll(m) >= 40) ? 0 : 1;
    }
}

// K1: fused prep. 800000 threads, three independent jobs:
//  (a) featB normalize (16B chunk per thread)
//  (b) per-(rel,dst) histogram + 16-slot bucket (1 edge per thread)
//  (c) BT weights (first 147456 threads): rows 0..1023 rel weights,
//      rows 1024..1151 self weight; BT[row][i] layout (B^T for the GEMM)
__global__ void k_prep(const void* __restrict__ feat_, const int* __restrict__ esrc,
                       const int* __restrict__ edst, const void* __restrict__ bases_,
                       const void* __restrict__ coeff_, const void* __restrict__ selfw_,
                       u16* __restrict__ featB, u16* __restrict__ BT,
                       int* __restrict__ cnt, u16* __restrict__ slots16,
                       const int* __restrict__ flag){
    int t = blockIdx.x * 256 + threadIdx.x;   // 0..799999 exact
    int isf = *flag;

    // (a) normalize feat chunk t (8 values -> 8 bf16)
    if (isf){
        const float4* ff = (const float4*)feat_;
        float4 a = ff[t*2], b = ff[t*2 + 1];
        uint4 o;
        o.x = (u32)f2bf(a.x) | ((u32)f2bf(a.y) << 16);
        o.y = (u32)f2bf(a.z) | ((u32)f2bf(a.w) << 16);
        o.z = (u32)f2bf(b.x) | ((u32)f2bf(b.y) << 16);
        o.w = (u32)f2bf(b.z) | ((u32)f2bf(b.w) << 16);
        ((uint4*)featB)[t] = o;
    } else {
        ((uint4*)featB)[t] = ((const uint4*)feat_)[t];
    }

    // (b) histogram + slots for edge t
    {
        int r = t / NE;
        int dst = edst[t];
        int src = esrc[t];
        int idx = r*NN + dst;
        int pos = atomicAdd(&cnt[idx], 1);
        if (pos < 16) slots16[(size_t)idx*16 + pos] = (u16)src;
    }

    // (c) weights elem t
    if (t < 147456){
        int row = t >> 7, i = t & 127;
        float v;
        if (isf){
            const float* bases = (const float*)bases_;
            const float* coeff = (const float*)coeff_;
            const float* selfw = (const float*)selfw_;
            if (row < 1024){
                int r = row >> 7, o = row & 127;
                v = 0.f;
                #pragma unroll
                for (int b = 0; b < 8; b++)
                    v += coeff[r*8 + b] * bases[(b*128 + i)*128 + o];
            } else {
                v = selfw[i*128 + (row - 1024)];
            }
        } else {
            const u16* bases = (const u16*)bases_;
            const u16* coeff = (const u16*)coeff_;
            const u16* selfw = (const u16*)selfw_;
            if (row < 1024){
                int r = row >> 7, o = row & 127;
                v = 0.f;
                #pragma unroll
                for (int b = 0; b < 8; b++)
                    v += bf2f(coeff[r*8 + b]) * bf2f(bases[(b*128 + i)*128 + o]);
            } else {
                v = bf2f(selfw[i*128 + (row - 1024)]);
            }
        }
        BT[row*128 + i] = f2bf(v);
    }
}

// K2: rf[nt][node][col] = featB @ BT_slice^T  (nt = 0..8; slice 8 = self weight)
// ZERO LDS, no barriers: afrag and bfrag both loaded direct from global
// (scattered 16-row x 16B reads, L2-hot), per-ks to keep VGPR low; direct
// scattered uint2 stores (round-5-verified epilogue). XCD-aware mapping keeps
// featB + BT L2-resident per XCD. Occupancy limited only by VGPR (~116 -> 4/SIMD).
__global__ __launch_bounds__(256) void k_gemm(
        const u16* __restrict__ featB, const u16* __restrict__ BT,
        u16* __restrict__ rf){
    int bid = blockIdx.x;                 // grid 3528 = 8 xcd * 49 mtl * 9 nt
    int xcd = bid & 7;
    int l   = bid >> 3;
    int mtl = l / 9;
    int nt  = l - mtl*9;
    int mt  = mtl*8 + xcd;
    if (mt >= 391) return;
    int node_base = mt * 128;
    int lane = threadIdx.x & 63, wid = threadIdx.x >> 6;
    int wm = wid >> 1, wn = wid & 1;      // 2x2 waves, 64x64 each
    int la = lane & 15, lb = lane >> 4;

    f32x4 c_[4][4];
    #pragma unroll
    for (int mf = 0; mf < 4; mf++)
        #pragma unroll
        for (int nf = 0; nf < 4; nf++)
            c_[mf][nf] = (f32x4)0.f;

    #pragma unroll
    for (int ks = 0; ks < 4; ks++){
        bf16x8 bfr[4], afr[4];
        #pragma unroll
        for (int nf = 0; nf < 4; nf++){
            int brow = nt*128 + wn*64 + nf*16 + la;
            bfr[nf] = *(const bf16x8*)&BT[brow*128 + ks*32 + lb*8];
        }
        #pragma unroll
        for (int mf = 0; mf < 4; mf++){
            int arow = node_base + wm*64 + mf*16 + la;   // may read <45KB past featB
            afr[mf] = *(const bf16x8*)&featB[(size_t)arow*128 + ks*32 + lb*8];
        }
        // swapped operands: M-dim = out-col (bfr), N-dim = node (afr)
        #pragma unroll
        for (int mf = 0; mf < 4; mf++)
            #pragma unroll
            for (int nf = 0; nf < 4; nf++)
                c_[mf][nf] = __builtin_amdgcn_mfma_f32_16x16x32_bf16(
                                bfr[nf], afr[mf], c_[mf][nf], 0, 0, 0);
    }

    // epilogue: lane holds node = base + wm*64+mf*16+la ; cols wn*64+nf*16+lb*4+(0..3)
    #pragma unroll
    for (int mf = 0; mf < 4; mf++){
        int node = node_base + wm*64 + mf*16 + la;
        if (node < NN){
            #pragma unroll
            for (int nf = 0; nf < 4; nf++){
                int col = wn*64 + nf*16 + lb*4;
                u32 lo = (u32)f2bf(c_[mf][nf][0]) | ((u32)f2bf(c_[mf][nf][1]) << 16);
                u32 hi = (u32)f2bf(c_[mf][nf][2]) | ((u32)f2bf(c_[mf][nf][3]) << 16);
                *(uint2*)&rf[((size_t)nt*NN + node)*128 + col] = make_uint2(lo, hi);
            }
        }
    }
}

// K3: gather + fused LayerNorm. One wave per dst node; lane holds cols (2l, 2l+1).
// Byte-identical to round 6 (verified fast, ~45us).
__global__ __launch_bounds__(256) void k_gather_ln(
        const u16* __restrict__ rf, const u16* __restrict__ slots16,
        const int* __restrict__ cnt, const void* __restrict__ gamma_,
        const void* __restrict__ beta_, void* __restrict__ out_,
        const int* __restrict__ flag){
    __shared__ int scnt[4][8];
    __shared__ u32 ssl[4][64];
    int isf = *flag;
    int wv = threadIdx.x >> 6;
    int lane = threadIdx.x & 63;
    int w = blockIdx.x*4 + wv;                 // dst node, grid exact 12500*4

    if (lane < 8) scnt[wv][lane] = cnt[lane*NN + w];
    const u32* s32 = (const u32*)slots16;
    ssl[wv][lane] = s32[((size_t)(lane >> 3)*NN + w)*8 + (lane & 7)];

    const u32* rf32 = (const u32*)rf;
    u32 sv = rf32[((size_t)8*NN + w)*64 + lane];
    float2 x;
    x.x = __uint_as_float(sv << 16);
    x.y = __uint_as_float(sv & 0xffff0000u);

    __builtin_amdgcn_s_waitcnt(0);             // drain own-wave LDS writes
    #pragma unroll
    for (int r = 0; r < 8; r++){
        int c = scnt[wv][r];
        float sc = 1.0f / (float)max(c, 1);
        if (c > 16) c = 16;
        float2 xr = make_float2(0.f, 0.f);
        #pragma unroll 4
        for (int p = 0; p < c; p++){
            u32 wsrc = ssl[wv][r*8 + (p >> 1)];
            int src = (wsrc >> ((p & 1) * 16)) & 0xffff;
            u32 v = rf32[((size_t)r*NN + src)*64 + lane];
            xr.x += __uint_as_float(v << 16);
            xr.y += __uint_as_float(v & 0xffff0000u);
        }
        x.x += xr.x * sc;
        x.y += xr.y * sc;
    }

    float s = x.x + x.y, q = x.x*x.x + x.y*x.y;
    #pragma unroll
    for (int off = 32; off; off >>= 1){
        s += __shfl_xor(s, off, 64);
        q += __shfl_xor(q, off, 64);
    }
    float mean = s * (1.f/128.f);
    float var  = q * (1.f/128.f) - mean*mean;
    float rstd = rsqrtf(fmaxf(var, 0.f) + 1e-5f);
    float g0, g1, b0, b1;
    if (isf){
        const float2* g = (const float2*)gamma_;
        const float2* b = (const float2*)beta_;
        float2 gv = g[lane], bv = b[lane];
        g0 = gv.x; g1 = gv.y; b0 = bv.x; b1 = bv.y;
    } else {
        u32 gv = ((const u32*)gamma_)[lane];
        u32 bv = ((const u32*)beta_)[lane];
        g0 = __uint_as_float(gv << 16); g1 = __uint_as_float(gv & 0xffff0000u);
        b0 = __uint_as_float(bv << 16); b1 = __uint_as_float(bv & 0xffff0000u);
    }
    float y0 = (x.x - mean)*rstd*g0 + b0;
    float y1 = (x.y - mean)*rstd*g1 + b1;
    if (isf){
        float2* o = (float2*)out_ + (size_t)w*64;
        o[lane] = make_float2(y0, y1);
    } else {
        u32* o = (u32*)out_ + (size_t)w*64;
        o[lane] = (u32)f2bf(y0) | ((u32)f2bf(y1) << 16);
    }
}

extern "C" void kernel_launch(void* const* d_in, const int* in_sizes, int n_in,
                              void* d_out, int out_size, void* d_ws, size_t ws_size,
                              hipStream_t stream){
    const void* feat  = d_in[0];
    const int*  esrc  = (const int*)d_in[1];
    const int*  edst  = (const int*)d_in[2];
    const void* bases = d_in[3];
    const void* coeff = d_in[4];
    const void* selfw = d_in[5];
    const void* gamma = d_in[6];
    const void* beta  = d_in[7];

    char* ws = (char*)d_ws;
    int*   flag    = (int*)(ws);                    // 256
    u16*   BT      = (u16*)(ws + 256);              // 294,912
    int*   cnt     = (int*)(ws + 295168);           // 1,600,000
    u16*   slots16 = (u16*)(ws + 1895168);          // 12,800,000
    u16*   featB   = (u16*)(ws + 14695168);         // 12,800,000
    u16*   rf      = (u16*)(ws + 27495168);         // 115,200,000 (9 slices; 8 = self)
    // total 142,695,168 B (harness grants >= 142,895,168, verified round 3/4)

    k_detect_zero<<<1563, 256, 0, stream>>>((const u16*)feat, flag, cnt);
    k_prep<<<3125, 256, 0, stream>>>(feat, esrc, edst, bases, coeff, selfw,
                                     featB, BT, cnt, slots16, flag);
    k_gemm<<<3528, 256, 0, stream>>>(featB, BT, rf);
    k_gather_ln<<<12500, 256, 0, stream>>>(rf, slots16, cnt, gamma, beta,
                                           d_out, flag);
}